// Round 8
// baseline (323.274 us; speedup 1.0000x reference)
//
#include <hip/hip_runtime.h>

typedef short s16x8 __attribute__((ext_vector_type(8)));
typedef short s16x4 __attribute__((ext_vector_type(4)));
typedef float f32x4 __attribute__((ext_vector_type(4)));

#define NB 16
#define NC 256
#define NL 4096
#define NH 1024
#define NE 128

// ws layout (bytes)
#define WS_YNT   0ull          // [B][L][C] bf16 transposed y   : 33554432
#define WS_PW1   33554432ull   // pw1 bf16 [1024][256]          : 524288
#define WS_PW2   34078720ull   // pw2 bf16 [256][1024]          : 524288
#define WS_AF    34603008ull   // a_film  [B][C] f32            : 16384
#define WS_BF    34619392ull   // b_film  [B][C] f32            : 16384
// per-block stat partials live in the first 32 KB of `out` (k3 fully
// overwrites out afterwards, stream-ordered) -> zero extra workspace.

#define MFMA16(a, b, c) __builtin_amdgcn_mfma_f32_16x16x32_bf16((a), (b), (c), 0, 0, 0)

static __device__ __forceinline__ short f2bf(float f) {
    unsigned int u = __float_as_uint(f);
    u = (u + 0x7fffu + ((u >> 16) & 1u)) >> 16;
    return (short)u;
}
static __device__ __forceinline__ float bf2f(short s) {
    return __uint_as_float(((unsigned int)(unsigned short)s) << 16);
}

// ---------------- K0: weight convert (vectorized f4 in / 8B out) ------------
__global__ __launch_bounds__(256) void k0_prep(const float4* __restrict__ pw1,
                                               const float4* __restrict__ pw2,
                                               s16x4* __restrict__ pw1b,
                                               s16x4* __restrict__ pw2b) {
    const int idx = blockIdx.x * 256 + threadIdx.x;   // grid 256 -> idx < 65536
    const float4 a = pw1[idx];
    const float4 b = pw2[idx];
    s16x4 oa, ob;
    oa[0] = f2bf(a.x); oa[1] = f2bf(a.y); oa[2] = f2bf(a.z); oa[3] = f2bf(a.w);
    ob[0] = f2bf(b.x); ob[1] = f2bf(b.y); ob[2] = f2bf(b.z); ob[3] = f2bf(b.w);
    pw1b[idx] = oa;
    pw2b[idx] = ob;
}

// ---------------- K1: depthwise conv (circular) + transpose-store + stats ----
// grid: B * 4 * 64 blocks; tile = (b, 64 c, 64 l). 256 threads.
// NO global atomics; one float2 partial per block into psum; k2 reduces.
// UNTOUCHED this round: the 4-way k3 split drops the rocprof top-5 threshold
// to ~38us so k1's true (post-atomic-fix) cost gets its first measurement.
__global__ __launch_bounds__(256) void k1_dwconv(const float* __restrict__ x,
                                                 const float* __restrict__ dw_w,
                                                 const float* __restrict__ dw_b,
                                                 short* __restrict__ ynt,
                                                 float2* __restrict__ psum) {
    __shared__ float xt[64][81];   // bank stride 81%32=17 (odd) -> <=2-way, free
    __shared__ float red1[4], red2[4];
    const int b = blockIdx.x >> 8;
    const int rem = blockIdx.x & 255;
    const int c0 = (rem >> 6) << 6;   // 4 c-blocks of 64
    const int l0 = (rem & 63) << 6;   // 64 l-blocks of 64
    const int t = threadIdx.x;

    // ---- stage 64 rows x 80 floats, coalesced float4 global loads ----
    const float* xb = x + ((size_t)(b * NC + c0)) * NL;
    {
#pragma unroll
        for (int j = 0; j < 5; ++j) {
            const int idx = t + 256 * j;
            const int row = idx / 20;
            const int col = idx - row * 20;
            const int lg = (l0 - 4 + col * 4) & (NL - 1);   // circular, 16B-aligned
            const float4 v = *(const float4*)(xb + (size_t)row * NL + lg);
            xt[row][col * 4 + 0] = v.x;
            xt[row][col * 4 + 1] = v.y;
            xt[row][col * 4 + 2] = v.z;
            xt[row][col * 4 + 3] = v.w;
        }
    }

    const int c = t & 63;       // lane == channel within tile
    const int w = t >> 6;       // wave id -> 16-l strip
    const float w0 = dw_w[(c0 + c) * 7 + 0], w1 = dw_w[(c0 + c) * 7 + 1],
                w2 = dw_w[(c0 + c) * 7 + 2], w3 = dw_w[(c0 + c) * 7 + 3],
                w4 = dw_w[(c0 + c) * 7 + 4], w5 = dw_w[(c0 + c) * 7 + 5],
                w6 = dw_w[(c0 + c) * 7 + 6];
    const float bb = dw_b[c0 + c];
    __syncthreads();

    float win0 = xt[c][w * 16 + 1], win1 = xt[c][w * 16 + 2], win2 = xt[c][w * 16 + 3],
          win3 = xt[c][w * 16 + 4], win4 = xt[c][w * 16 + 5], win5 = xt[c][w * 16 + 6],
          win6 = xt[c][w * 16 + 7];
    float s1 = 0.f, s2 = 0.f;
    short* yo = ynt + ((size_t)(b * NL + l0 + w * 16)) * NC + c0 + c;
#pragma unroll
    for (int i = 0; i < 16; ++i) {
        const float y = bb + w0 * win0 + w1 * win1 + w2 * win2 + w3 * win3 +
                        w4 * win4 + w5 * win5 + w6 * win6;
        s1 += y;
        s2 += y * y;
        yo[(size_t)i * NC] = f2bf(y);
        win0 = win1; win1 = win2; win2 = win3; win3 = win4; win4 = win5; win5 = win6;
        win6 = xt[c][w * 16 + i + 8];
    }
    for (int off = 32; off; off >>= 1) {
        s1 += __shfl_down(s1, off, 64);
        s2 += __shfl_down(s2, off, 64);
    }
    if ((t & 63) == 0) { red1[w] = s1; red2[w] = s2; }
    __syncthreads();
    if (t == 0) {
        psum[blockIdx.x] = make_float2(red1[0] + red1[1] + red1[2] + red1[3],
                                       red2[0] + red2[1] + red2[2] + red2[3]);
    }
}

// ---------------- K2: reduce partials + FiLM -> per-(b,c) affine --------------
__global__ __launch_bounds__(256) void k2_finalize(const float* __restrict__ tin,
                                                   const float* __restrict__ fw,
                                                   const float* __restrict__ fb,
                                                   const float2* __restrict__ psum,
                                                   float* __restrict__ afilm,
                                                   float* __restrict__ bfilm) {
    __shared__ float r1[4], r2[4];
    const int b = blockIdx.x;
    const int c = threadIdx.x;

    // reduce this batch's 256 block partials
    const float2 v = psum[b * 256 + c];
    float s1 = v.x, s2 = v.y;
    for (int off = 32; off; off >>= 1) {
        s1 += __shfl_down(s1, off, 64);
        s2 += __shfl_down(s2, off, 64);
    }
    if ((c & 63) == 0) { r1[c >> 6] = s1; r2[c >> 6] = s2; }
    __syncthreads();
    const float sum1 = r1[0] + r1[1] + r1[2] + r1[3];
    const float sum2 = r2[0] + r2[1] + r2[2] + r2[3];

    const float n = (float)(NC * NL);
    const float mu = sum1 / n;
    const float var = sum2 / n - mu * mu;
    const float rs = rsqrtf(var + 1e-6f);

    const f32x4* tv = (const f32x4*)(tin + b * NE);
    const f32x4* wA = (const f32x4*)(fw + (size_t)c * NE);
    const f32x4* wB = (const f32x4*)(fw + (size_t)(NC + c) * NE);
    float sc = 0.f, sh = 0.f;
#pragma unroll
    for (int e = 0; e < NE / 4; ++e) {
        f32x4 tq = tv[e], aq = wA[e], bq = wB[e];
        sc += tq[0] * aq[0] + tq[1] * aq[1] + tq[2] * aq[2] + tq[3] * aq[3];
        sh += tq[0] * bq[0] + tq[1] * bq[1] + tq[2] * bq[2] + tq[3] * bq[3];
    }
    sc += fb[c];
    sh += fb[NC + c];
    const float A = rs * (1.f + sc);
    afilm[b * NC + c] = A;
    bfilm[b * NC + c] = sh - mu * A;
}

// ---------------- K3: fused yn -> GEMM1(relu) -> GEMM2 -> residual ----------
// grid: (NB/4) * (L/64) blocks per dispatch (b0 = batch offset), 256 threads.
// R6 body (best measured: 148.3us as one dispatch): double-buffered hs, ONE
// __syncthreads per chunk, a2p issued early in source (compiler may sink --
// that variant measured best and spills nothing). Split 4-way for diagnosis.
__global__ __launch_bounds__(256, 2) void k3_gemm(
    const short* __restrict__ ynt, const short* __restrict__ pw1b,
    const short* __restrict__ pw2b, const float* __restrict__ pb1,
    const float* __restrict__ pb2, const float* __restrict__ afilm,
    const float* __restrict__ bfilm, const float* __restrict__ gamma,
    const float* __restrict__ x, float* __restrict__ out, int b0) {
    __shared__ short yn[64 * 264];      // [l][c], stride 264 (132 words == 4 mod 32)
    __shared__ short hs[2][64 * 136];   // [l][d], stride 136 (68 words  == 4 mod 32)

    const int b = (blockIdx.x >> 6) + b0;
    const int l0 = (blockIdx.x & 63) << 6;
    const int t = threadIdx.x;
    const int lane = t & 63, wid = t >> 6;
    const int ln = lane & 15, quad = lane >> 4;

    // ---- stage yn tile with the fused GroupNorm+FiLM affine ----
    {
        const int c8 = (t & 31) * 8;
        const int lrow = t >> 5;
        const f32x4 a0 = *(const f32x4*)(afilm + b * NC + c8);
        const f32x4 a1 = *(const f32x4*)(afilm + b * NC + c8 + 4);
        const f32x4 f0 = *(const f32x4*)(bfilm + b * NC + c8);
        const f32x4 f1 = *(const f32x4*)(bfilm + b * NC + c8 + 4);
        const short* ys = ynt + ((size_t)(b * NL + l0)) * NC + c8;
#pragma unroll
        for (int p = 0; p < 8; ++p) {
            const int l = p * 8 + lrow;
            s16x8 v = *(const s16x8*)(ys + (size_t)l * NC);
            s16x8 o;
#pragma unroll
            for (int j = 0; j < 4; ++j) {
                o[j]     = f2bf(a0[j] * bf2f(v[j])     + f0[j]);
                o[4 + j] = f2bf(a1[j] * bf2f(v[4 + j]) + f1[j]);
            }
            *(s16x8*)(yn + l * 264 + c8) = o;
        }
    }

    const short* A1b = pw1b + (size_t)(32 * wid + ln) * NC + quad * 8;
    const short* A2b = pw2b + (size_t)(64 * wid + ln) * NH + quad * 8;

    // A1(0) first half issued before the barrier (drained during it)
    s16x8 a1p[16];
#pragma unroll
    for (int kk = 0; kk < 4; ++kk) {
        a1p[2 * kk + 0] = *(const s16x8*)(A1b + kk * 32);
        a1p[2 * kk + 1] = *(const s16x8*)(A1b + 16 * NC + kk * 32);
    }
    __syncthreads();   // yn ready
#pragma unroll
    for (int kk = 4; kk < 8; ++kk) {
        a1p[2 * kk + 0] = *(const s16x8*)(A1b + kk * 32);
        a1p[2 * kk + 1] = *(const s16x8*)(A1b + 16 * NC + kk * 32);
    }

    // ---- a2p(0) prefetch (early in source; neutral-best variant) ----
    s16x8 a2p[16];
#pragma unroll
    for (int kk = 0; kk < 4; ++kk) {
#pragma unroll
        for (int m = 0; m < 4; ++m) {
            a2p[4 * kk + m] = *(const s16x8*)(A2b + m * 16 * NH + kk * 32);
        }
    }

    // ---- GEMM1(0) ----
    f32x4 acc1[2][4] = {};
#pragma unroll
    for (int kk = 0; kk < 8; ++kk) {
        const int kq = kk * 32 + quad * 8;
        s16x8 b0v = *(const s16x8*)(yn + (0 * 16 + ln) * 264 + kq);
        s16x8 b1v = *(const s16x8*)(yn + (1 * 16 + ln) * 264 + kq);
        s16x8 b2v = *(const s16x8*)(yn + (2 * 16 + ln) * 264 + kq);
        s16x8 b3v = *(const s16x8*)(yn + (3 * 16 + ln) * 264 + kq);
        acc1[0][0] = MFMA16(a1p[2 * kk], b0v, acc1[0][0]);
        acc1[0][1] = MFMA16(a1p[2 * kk], b1v, acc1[0][1]);
        acc1[0][2] = MFMA16(a1p[2 * kk], b2v, acc1[0][2]);
        acc1[0][3] = MFMA16(a1p[2 * kk], b3v, acc1[0][3]);
        acc1[1][0] = MFMA16(a1p[2 * kk + 1], b0v, acc1[1][0]);
        acc1[1][1] = MFMA16(a1p[2 * kk + 1], b1v, acc1[1][1]);
        acc1[1][2] = MFMA16(a1p[2 * kk + 1], b2v, acc1[1][2]);
        acc1[1][3] = MFMA16(a1p[2 * kk + 1], b3v, acc1[1][3]);
    }

    f32x4 acc2[4][4] = {};

#pragma unroll 1
    for (int ch = 0; ch < 7; ++ch) {
        const int dc0 = ch * 128;
        // ---- hs[ch&1] <- relu(acc1 + b1) ----
        short* hw = &hs[ch & 1][0];
#pragma unroll
        for (int mf = 0; mf < 2; ++mf) {
            const int dbase = 32 * wid + mf * 16 + quad * 4;
            const f32x4 b1v = *(const f32x4*)(pb1 + dc0 + dbase);
#pragma unroll
            for (int nf = 0; nf < 4; ++nf) {
                const int l = nf * 16 + ln;
                s16x4 hv;
#pragma unroll
                for (int r = 0; r < 4; ++r) {
                    hv[r] = f2bf(fmaxf(acc1[mf][nf][r] + b1v[r], 0.f));
                }
                *(s16x4*)(hw + l * 136 + dbase) = hv;
            }
        }
        __syncthreads();   // hs[ch&1] visible
        // ---- A1(ch+1) first half ----
        const short* A1n = A1b + (size_t)(dc0 + 128) * NC;
#pragma unroll
        for (int kk = 0; kk < 4; ++kk) {
            a1p[2 * kk + 0] = *(const s16x8*)(A1n + kk * 32);
            a1p[2 * kk + 1] = *(const s16x8*)(A1n + 16 * NC + kk * 32);
        }
        // ---- GEMM2(ch): acc2 += pw2[:, chunk] . h ----
        const short* hr = &hs[ch & 1][0];
#pragma unroll
        for (int kk = 0; kk < 4; ++kk) {
            const int kq = kk * 32 + quad * 8;
            s16x8 h0 = *(const s16x8*)(hr + (0 * 16 + ln) * 136 + kq);
            s16x8 h1 = *(const s16x8*)(hr + (1 * 16 + ln) * 136 + kq);
            s16x8 h2 = *(const s16x8*)(hr + (2 * 16 + ln) * 136 + kq);
            s16x8 h3 = *(const s16x8*)(hr + (3 * 16 + ln) * 136 + kq);
            acc2[0][0] = MFMA16(a2p[4 * kk + 0], h0, acc2[0][0]);
            acc2[0][1] = MFMA16(a2p[4 * kk + 0], h1, acc2[0][1]);
            acc2[0][2] = MFMA16(a2p[4 * kk + 0], h2, acc2[0][2]);
            acc2[0][3] = MFMA16(a2p[4 * kk + 0], h3, acc2[0][3]);
            acc2[1][0] = MFMA16(a2p[4 * kk + 1], h0, acc2[1][0]);
            acc2[1][1] = MFMA16(a2p[4 * kk + 1], h1, acc2[1][1]);
            acc2[1][2] = MFMA16(a2p[4 * kk + 1], h2, acc2[1][2]);
            acc2[1][3] = MFMA16(a2p[4 * kk + 1], h3, acc2[1][3]);
            acc2[2][0] = MFMA16(a2p[4 * kk + 2], h0, acc2[2][0]);
            acc2[2][1] = MFMA16(a2p[4 * kk + 2], h1, acc2[2][1]);
            acc2[2][2] = MFMA16(a2p[4 * kk + 2], h2, acc2[2][2]);
            acc2[2][3] = MFMA16(a2p[4 * kk + 2], h3, acc2[2][3]);
            acc2[3][0] = MFMA16(a2p[4 * kk + 3], h0, acc2[3][0]);
            acc2[3][1] = MFMA16(a2p[4 * kk + 3], h1, acc2[3][1]);
            acc2[3][2] = MFMA16(a2p[4 * kk + 3], h2, acc2[3][2]);
            acc2[3][3] = MFMA16(a2p[4 * kk + 3], h3, acc2[3][3]);
        }
        // ---- A1(ch+1) second half ----
#pragma unroll
        for (int kk = 4; kk < 8; ++kk) {
            a1p[2 * kk + 0] = *(const s16x8*)(A1n + kk * 32);
            a1p[2 * kk + 1] = *(const s16x8*)(A1n + 16 * NC + kk * 32);
        }
        // ---- a2p(ch+1) prefetch ----
        {
            const short* A2n = A2b + dc0 + 128;
#pragma unroll
            for (int kk = 0; kk < 4; ++kk) {
#pragma unroll
                for (int m = 0; m < 4; ++m) {
                    a2p[4 * kk + m] = *(const s16x8*)(A2n + m * 16 * NH + kk * 32);
                }
            }
        }
        // ---- GEMM1(ch+1) ----
#pragma unroll
        for (int i = 0; i < 2; ++i)
#pragma unroll
            for (int j = 0; j < 4; ++j) acc1[i][j] = (f32x4){0.f, 0.f, 0.f, 0.f};
#pragma unroll
        for (int kk = 0; kk < 8; ++kk) {
            const int kq = kk * 32 + quad * 8;
            s16x8 b0v = *(const s16x8*)(yn + (0 * 16 + ln) * 264 + kq);
            s16x8 b1v = *(const s16x8*)(yn + (1 * 16 + ln) * 264 + kq);
            s16x8 b2v = *(const s16x8*)(yn + (2 * 16 + ln) * 264 + kq);
            s16x8 b3v = *(const s16x8*)(yn + (3 * 16 + ln) * 264 + kq);
            acc1[0][0] = MFMA16(a1p[2 * kk], b0v, acc1[0][0]);
            acc1[0][1] = MFMA16(a1p[2 * kk], b1v, acc1[0][1]);
            acc1[0][2] = MFMA16(a1p[2 * kk], b2v, acc1[0][2]);
            acc1[0][3] = MFMA16(a1p[2 * kk], b3v, acc1[0][3]);
            acc1[1][0] = MFMA16(a1p[2 * kk + 1], b0v, acc1[1][0]);
            acc1[1][1] = MFMA16(a1p[2 * kk + 1], b1v, acc1[1][1]);
            acc1[1][2] = MFMA16(a1p[2 * kk + 1], b2v, acc1[1][2]);
            acc1[1][3] = MFMA16(a1p[2 * kk + 1], b3v, acc1[1][3]);
        }
    }

    // ---- tail: chunk 7 GEMM2 (a2p(7) prefetched in iter 6) ----
    {
        short* hw = &hs[1][0];
#pragma unroll
        for (int mf = 0; mf < 2; ++mf) {
            const int dbase = 32 * wid + mf * 16 + quad * 4;
            const f32x4 b1v = *(const f32x4*)(pb1 + 7 * 128 + dbase);
#pragma unroll
            for (int nf = 0; nf < 4; ++nf) {
                const int l = nf * 16 + ln;
                s16x4 hv;
#pragma unroll
                for (int r = 0; r < 4; ++r) {
                    hv[r] = f2bf(fmaxf(acc1[mf][nf][r] + b1v[r], 0.f));
                }
                *(s16x4*)(hw + l * 136 + dbase) = hv;
            }
        }
        __syncthreads();
        const short* hr = &hs[1][0];
#pragma unroll
        for (int kk = 0; kk < 4; ++kk) {
            const int kq = kk * 32 + quad * 8;
            s16x8 h0 = *(const s16x8*)(hr + (0 * 16 + ln) * 136 + kq);
            s16x8 h1 = *(const s16x8*)(hr + (1 * 16 + ln) * 136 + kq);
            s16x8 h2 = *(const s16x8*)(hr + (2 * 16 + ln) * 136 + kq);
            s16x8 h3 = *(const s16x8*)(hr + (3 * 16 + ln) * 136 + kq);
            acc2[0][0] = MFMA16(a2p[4 * kk + 0], h0, acc2[0][0]);
            acc2[0][1] = MFMA16(a2p[4 * kk + 0], h1, acc2[0][1]);
            acc2[0][2] = MFMA16(a2p[4 * kk + 0], h2, acc2[0][2]);
            acc2[0][3] = MFMA16(a2p[4 * kk + 0], h3, acc2[0][3]);
            acc2[1][0] = MFMA16(a2p[4 * kk + 1], h0, acc2[1][0]);
            acc2[1][1] = MFMA16(a2p[4 * kk + 1], h1, acc2[1][1]);
            acc2[1][2] = MFMA16(a2p[4 * kk + 1], h2, acc2[1][2]);
            acc2[1][3] = MFMA16(a2p[4 * kk + 1], h3, acc2[1][3]);
            acc2[2][0] = MFMA16(a2p[4 * kk + 2], h0, acc2[2][0]);
            acc2[2][1] = MFMA16(a2p[4 * kk + 2], h1, acc2[2][1]);
            acc2[2][2] = MFMA16(a2p[4 * kk + 2], h2, acc2[2][2]);
            acc2[2][3] = MFMA16(a2p[4 * kk + 2], h3, acc2[2][3]);
            acc2[3][0] = MFMA16(a2p[4 * kk + 3], h0, acc2[3][0]);
            acc2[3][1] = MFMA16(a2p[4 * kk + 3], h1, acc2[3][1]);
            acc2[3][2] = MFMA16(a2p[4 * kk + 3], h2, acc2[3][2]);
            acc2[3][3] = MFMA16(a2p[4 * kk + 3], h3, acc2[3][3]);
        }
    }

    // ---- epilogue: out = x + gamma * (acc2 + b2) ----
#pragma unroll
    for (int mf2 = 0; mf2 < 4; ++mf2) {
        const int cbase = 64 * wid + mf2 * 16 + quad * 4;
        const f32x4 g4 = *(const f32x4*)(gamma + cbase);
        const f32x4 b4 = *(const f32x4*)(pb2 + cbase);
#pragma unroll
        for (int r = 0; r < 4; ++r) {
            const int c = cbase + r;
            const size_t base = ((size_t)(b * NC + c)) * NL + l0 + ln;
            const float* xr = x + base;
            float* orow = out + base;
#pragma unroll
            for (int nf2 = 0; nf2 < 4; ++nf2) {
                orow[nf2 * 16] = xr[nf2 * 16] + g4[r] * (acc2[mf2][nf2][r] + b4[r]);
            }
        }
    }
}

extern "C" void kernel_launch(void* const* d_in, const int* in_sizes, int n_in,
                              void* d_out, int out_size, void* d_ws, size_t ws_size,
                              hipStream_t stream) {
    (void)in_sizes; (void)n_in; (void)out_size; (void)ws_size;
    const float* x      = (const float*)d_in[0];
    const float* tin    = (const float*)d_in[1];
    const float* dw_w   = (const float*)d_in[2];
    const float* dw_b   = (const float*)d_in[3];
    const float* film_w = (const float*)d_in[4];
    const float* film_b = (const float*)d_in[5];
    const float* pw1_w  = (const float*)d_in[6];
    const float* pw1_b  = (const float*)d_in[7];
    const float* pw2_w  = (const float*)d_in[8];
    const float* pw2_b  = (const float*)d_in[9];
    const float* gamma  = (const float*)d_in[10];
    float* out = (float*)d_out;

    char* ws = (char*)d_ws;
    short* ynt  = (short*)(ws + WS_YNT);
    short* pw1b = (short*)(ws + WS_PW1);
    short* pw2b = (short*)(ws + WS_PW2);
    float* afilm = (float*)(ws + WS_AF);
    float* bfilm = (float*)(ws + WS_BF);
    // stat partials: first 32 KB of out (k3 overwrites all of out later)
    float2* psum = (float2*)d_out;

    hipLaunchKernelGGL(k0_prep, dim3(256), dim3(256), 0, stream,
                       (const float4*)pw1_w, (const float4*)pw2_w,
                       (s16x4*)pw1b, (s16x4*)pw2b);
    hipLaunchKernelGGL(k1_dwconv, dim3(NB * 256), dim3(256), 0, stream,
                       x, dw_w, dw_b, ynt, psum);
    hipLaunchKernelGGL(k2_finalize, dim3(NB), dim3(256), 0, stream,
                       tin, film_w, film_b, psum, afilm, bfilm);
    hipLaunchKernelGGL(k3_gemm, dim3((NB / 4) * (NL / 64)), dim3(256), 0, stream,
                       ynt, pw1b, pw2b, pw1_b, pw2_b, afilm, bfilm, gamma, x, out, 0);
    hipLaunchKernelGGL(k3_gemm, dim3((NB / 4) * (NL / 64)), dim3(256), 0, stream,
                       ynt, pw1b, pw2b, pw1_b, pw2_b, afilm, bfilm, gamma, x, out, 4);
    hipLaunchKernelGGL(k3_gemm, dim3((NB / 4) * (NL / 64)), dim3(256), 0, stream,
                       ynt, pw1b, pw2b, pw1_b, pw2_b, afilm, bfilm, gamma, x, out, 8);
    hipLaunchKernelGGL(k3_gemm, dim3((NB / 4) * (NL / 64)), dim3(256), 0, stream,
                       ynt, pw1b, pw2b, pw1_b, pw2_b, afilm, bfilm, gamma, x, out, 12);
}

// Round 9
// 299.778 us; speedup vs baseline: 1.0784x; 1.0784x over previous
//
#include <hip/hip_runtime.h>

typedef short s16x8 __attribute__((ext_vector_type(8)));
typedef short s16x4 __attribute__((ext_vector_type(4)));
typedef float f32x4 __attribute__((ext_vector_type(4)));

#define NB 16
#define NC 256
#define NL 4096
#define NH 1024
#define NE 128

// ws layout (bytes)
#define WS_YNT   0ull          // [B][L][C] bf16 transposed y   : 33554432
#define WS_PW1   33554432ull   // pw1 bf16 [1024][256]          : 524288
#define WS_PW2   34078720ull   // pw2 bf16 [256][1024]          : 524288
#define WS_PSUM  34603008ull   // [4096] float2 stat partials  : 32768
// (psum must NOT alias `out`: k3 both reads psum and writes out now)

#define MFMA16(a, b, c) __builtin_amdgcn_mfma_f32_16x16x32_bf16((a), (b), (c), 0, 0, 0)

static __device__ __forceinline__ short f2bf(float f) {
    unsigned int u = __float_as_uint(f);
    u = (u + 0x7fffu + ((u >> 16) & 1u)) >> 16;
    return (short)u;
}
static __device__ __forceinline__ float bf2f(short s) {
    return __uint_as_float(((unsigned int)(unsigned short)s) << 16);
}

// ---------------- K01: dwconv+stats (blocks 0..4095) | weight cvt (4096..4351)
// Merged to cut one dispatch + inter-kernel gap (~15us measured overhead/launch).
__global__ __launch_bounds__(256) void k01_fused(const float* __restrict__ x,
                                                 const float* __restrict__ dw_w,
                                                 const float* __restrict__ dw_b,
                                                 short* __restrict__ ynt,
                                                 float2* __restrict__ psum,
                                                 const float4* __restrict__ pw1,
                                                 const float4* __restrict__ pw2,
                                                 s16x4* __restrict__ pw1b,
                                                 s16x4* __restrict__ pw2b) {
    __shared__ float xt[64][81];   // bank stride 81%32=17 (odd) -> <=2-way, free
    __shared__ float red1[4], red2[4];
    const int t = threadIdx.x;

    if (blockIdx.x >= NB * 256) {
        // ---- weight conversion path: 256 blocks cover 65536 float4s ----
        const int idx = (blockIdx.x - NB * 256) * 256 + t;
        const float4 a = pw1[idx];
        const float4 bq = pw2[idx];
        s16x4 oa, ob;
        oa[0] = f2bf(a.x); oa[1] = f2bf(a.y); oa[2] = f2bf(a.z); oa[3] = f2bf(a.w);
        ob[0] = f2bf(bq.x); ob[1] = f2bf(bq.y); ob[2] = f2bf(bq.z); ob[3] = f2bf(bq.w);
        pw1b[idx] = oa;
        pw2b[idx] = ob;
        return;
    }

    const int b = blockIdx.x >> 8;
    const int rem = blockIdx.x & 255;
    const int c0 = (rem >> 6) << 6;   // 4 c-blocks of 64
    const int l0 = (rem & 63) << 6;   // 64 l-blocks of 64

    // ---- stage 64 rows x 80 floats, coalesced float4 global loads ----
    const float* xb = x + ((size_t)(b * NC + c0)) * NL;
    {
#pragma unroll
        for (int j = 0; j < 5; ++j) {
            const int idx = t + 256 * j;
            const int row = idx / 20;
            const int col = idx - row * 20;
            const int lg = (l0 - 4 + col * 4) & (NL - 1);   // circular, 16B-aligned
            const float4 v = *(const float4*)(xb + (size_t)row * NL + lg);
            xt[row][col * 4 + 0] = v.x;
            xt[row][col * 4 + 1] = v.y;
            xt[row][col * 4 + 2] = v.z;
            xt[row][col * 4 + 3] = v.w;
        }
    }

    const int c = t & 63;       // lane == channel within tile
    const int w = t >> 6;       // wave id -> 16-l strip
    const float w0 = dw_w[(c0 + c) * 7 + 0], w1 = dw_w[(c0 + c) * 7 + 1],
                w2 = dw_w[(c0 + c) * 7 + 2], w3 = dw_w[(c0 + c) * 7 + 3],
                w4 = dw_w[(c0 + c) * 7 + 4], w5 = dw_w[(c0 + c) * 7 + 5],
                w6 = dw_w[(c0 + c) * 7 + 6];
    const float bb = dw_b[c0 + c];
    __syncthreads();

    float win0 = xt[c][w * 16 + 1], win1 = xt[c][w * 16 + 2], win2 = xt[c][w * 16 + 3],
          win3 = xt[c][w * 16 + 4], win4 = xt[c][w * 16 + 5], win5 = xt[c][w * 16 + 6],
          win6 = xt[c][w * 16 + 7];
    float s1 = 0.f, s2 = 0.f;
    short* yo = ynt + ((size_t)(b * NL + l0 + w * 16)) * NC + c0 + c;
#pragma unroll
    for (int i = 0; i < 16; ++i) {
        const float y = bb + w0 * win0 + w1 * win1 + w2 * win2 + w3 * win3 +
                        w4 * win4 + w5 * win5 + w6 * win6;
        s1 += y;
        s2 += y * y;
        yo[(size_t)i * NC] = f2bf(y);
        win0 = win1; win1 = win2; win2 = win3; win3 = win4; win4 = win5; win5 = win6;
        win6 = xt[c][w * 16 + i + 8];
    }
    for (int off = 32; off; off >>= 1) {
        s1 += __shfl_down(s1, off, 64);
        s2 += __shfl_down(s2, off, 64);
    }
    if ((t & 63) == 0) { red1[w] = s1; red2[w] = s2; }
    __syncthreads();
    if (t == 0) {
        psum[blockIdx.x] = make_float2(red1[0] + red1[1] + red1[2] + red1[3],
                                       red2[0] + red2[1] + red2[2] + red2[3]);
    }
}

// ---------------- K3: stats+FiLM prologue -> yn -> GEMM1(relu) -> GEMM2 ------
// grid: B * (L/64) blocks, 256 threads = 4 waves. Single dispatch.
// k2 folded in: every block redundantly reduces its batch's 256 psum partials
// (2 KB) + computes the FiLM matvec (fw 256 KB, L2-resident) -- deterministic
// identical order across blocks -> bit-identical affine. Saves one dispatch +
// gap. Main loop: R6 body verbatim (best measured 148.2us single-dispatch).
__global__ __launch_bounds__(256, 2) void k3_gemm(
    const short* __restrict__ ynt, const short* __restrict__ pw1b,
    const short* __restrict__ pw2b, const float* __restrict__ pb1,
    const float* __restrict__ pb2, const float* __restrict__ tin,
    const float* __restrict__ fw, const float* __restrict__ fb,
    const float2* __restrict__ psum, const float* __restrict__ gamma,
    const float* __restrict__ x, float* __restrict__ out) {
    __shared__ short yn[64 * 264];      // [l][c], stride 264 (132 words == 4 mod 32)
    __shared__ short hs[2][64 * 136];   // [l][d], stride 136 (68 words  == 4 mod 32)
    __shared__ float afs[NC], bfs[NC];  // FiLM affine staged per block (+2 KB)
    __shared__ float r1[4], r2[4];

    const int b = blockIdx.x >> 6;
    const int l0 = (blockIdx.x & 63) << 6;
    const int t = threadIdx.x;
    const int lane = t & 63, wid = t >> 6;
    const int ln = lane & 15, quad = lane >> 4;

    // ---- folded k2: reduce psum(b) + FiLM -> afs/bfs (c == t) ----
    {
        const float2 v = psum[b * 256 + t];
        float s1 = v.x, s2 = v.y;
        for (int off = 32; off; off >>= 1) {
            s1 += __shfl_down(s1, off, 64);
            s2 += __shfl_down(s2, off, 64);
        }
        if ((t & 63) == 0) { r1[t >> 6] = s1; r2[t >> 6] = s2; }
        __syncthreads();
        const float sum1 = r1[0] + r1[1] + r1[2] + r1[3];
        const float sum2 = r2[0] + r2[1] + r2[2] + r2[3];
        const float n = (float)(NC * NL);
        const float mu = sum1 / n;
        const float var = sum2 / n - mu * mu;
        const float rs = rsqrtf(var + 1e-6f);

        const f32x4* tv = (const f32x4*)(tin + b * NE);
        const f32x4* wA = (const f32x4*)(fw + (size_t)t * NE);
        const f32x4* wB = (const f32x4*)(fw + (size_t)(NC + t) * NE);
        float sc = 0.f, sh = 0.f;
#pragma unroll
        for (int e = 0; e < NE / 4; ++e) {
            f32x4 tq = tv[e], aq = wA[e], bq = wB[e];
            sc += tq[0] * aq[0] + tq[1] * aq[1] + tq[2] * aq[2] + tq[3] * aq[3];
            sh += tq[0] * bq[0] + tq[1] * bq[1] + tq[2] * bq[2] + tq[3] * bq[3];
        }
        sc += fb[t];
        sh += fb[NC + t];
        const float A = rs * (1.f + sc);
        afs[t] = A;
        bfs[t] = sh - mu * A;
        __syncthreads();
    }

    // ---- stage yn tile with the fused GroupNorm+FiLM affine (from LDS) ----
    {
        const int c8 = (t & 31) * 8;
        const int lrow = t >> 5;
        const f32x4 a0 = *(const f32x4*)(afs + c8);
        const f32x4 a1 = *(const f32x4*)(afs + c8 + 4);
        const f32x4 f0 = *(const f32x4*)(bfs + c8);
        const f32x4 f1 = *(const f32x4*)(bfs + c8 + 4);
        const short* ys = ynt + ((size_t)(b * NL + l0)) * NC + c8;
#pragma unroll
        for (int p = 0; p < 8; ++p) {
            const int l = p * 8 + lrow;
            s16x8 v = *(const s16x8*)(ys + (size_t)l * NC);
            s16x8 o;
#pragma unroll
            for (int j = 0; j < 4; ++j) {
                o[j]     = f2bf(a0[j] * bf2f(v[j])     + f0[j]);
                o[4 + j] = f2bf(a1[j] * bf2f(v[4 + j]) + f1[j]);
            }
            *(s16x8*)(yn + l * 264 + c8) = o;
        }
    }

    const short* A1b = pw1b + (size_t)(32 * wid + ln) * NC + quad * 8;
    const short* A2b = pw2b + (size_t)(64 * wid + ln) * NH + quad * 8;

    // A1(0) first half issued before the barrier (drained during it)
    s16x8 a1p[16];
#pragma unroll
    for (int kk = 0; kk < 4; ++kk) {
        a1p[2 * kk + 0] = *(const s16x8*)(A1b + kk * 32);
        a1p[2 * kk + 1] = *(const s16x8*)(A1b + 16 * NC + kk * 32);
    }
    __syncthreads();   // yn ready
#pragma unroll
    for (int kk = 4; kk < 8; ++kk) {
        a1p[2 * kk + 0] = *(const s16x8*)(A1b + kk * 32);
        a1p[2 * kk + 1] = *(const s16x8*)(A1b + 16 * NC + kk * 32);
    }

    // ---- a2p(0) prefetch (early in source) ----
    s16x8 a2p[16];
#pragma unroll
    for (int kk = 0; kk < 4; ++kk) {
#pragma unroll
        for (int m = 0; m < 4; ++m) {
            a2p[4 * kk + m] = *(const s16x8*)(A2b + m * 16 * NH + kk * 32);
        }
    }

    // ---- GEMM1(0) ----
    f32x4 acc1[2][4] = {};
#pragma unroll
    for (int kk = 0; kk < 8; ++kk) {
        const int kq = kk * 32 + quad * 8;
        s16x8 b0v = *(const s16x8*)(yn + (0 * 16 + ln) * 264 + kq);
        s16x8 b1v = *(const s16x8*)(yn + (1 * 16 + ln) * 264 + kq);
        s16x8 b2v = *(const s16x8*)(yn + (2 * 16 + ln) * 264 + kq);
        s16x8 b3v = *(const s16x8*)(yn + (3 * 16 + ln) * 264 + kq);
        acc1[0][0] = MFMA16(a1p[2 * kk], b0v, acc1[0][0]);
        acc1[0][1] = MFMA16(a1p[2 * kk], b1v, acc1[0][1]);
        acc1[0][2] = MFMA16(a1p[2 * kk], b2v, acc1[0][2]);
        acc1[0][3] = MFMA16(a1p[2 * kk], b3v, acc1[0][3]);
        acc1[1][0] = MFMA16(a1p[2 * kk + 1], b0v, acc1[1][0]);
        acc1[1][1] = MFMA16(a1p[2 * kk + 1], b1v, acc1[1][1]);
        acc1[1][2] = MFMA16(a1p[2 * kk + 1], b2v, acc1[1][2]);
        acc1[1][3] = MFMA16(a1p[2 * kk + 1], b3v, acc1[1][3]);
    }

    f32x4 acc2[4][4] = {};

#pragma unroll 1
    for (int ch = 0; ch < 7; ++ch) {
        const int dc0 = ch * 128;
        // ---- hs[ch&1] <- relu(acc1 + b1) ----
        short* hw = &hs[ch & 1][0];
#pragma unroll
        for (int mf = 0; mf < 2; ++mf) {
            const int dbase = 32 * wid + mf * 16 + quad * 4;
            const f32x4 b1v = *(const f32x4*)(pb1 + dc0 + dbase);
#pragma unroll
            for (int nf = 0; nf < 4; ++nf) {
                const int l = nf * 16 + ln;
                s16x4 hv;
#pragma unroll
                for (int r = 0; r < 4; ++r) {
                    hv[r] = f2bf(fmaxf(acc1[mf][nf][r] + b1v[r], 0.f));
                }
                *(s16x4*)(hw + l * 136 + dbase) = hv;
            }
        }
        __syncthreads();   // hs[ch&1] visible
        // ---- A1(ch+1) first half ----
        const short* A1n = A1b + (size_t)(dc0 + 128) * NC;
#pragma unroll
        for (int kk = 0; kk < 4; ++kk) {
            a1p[2 * kk + 0] = *(const s16x8*)(A1n + kk * 32);
            a1p[2 * kk + 1] = *(const s16x8*)(A1n + 16 * NC + kk * 32);
        }
        // ---- GEMM2(ch): acc2 += pw2[:, chunk] . h ----
        const short* hr = &hs[ch & 1][0];
#pragma unroll
        for (int kk = 0; kk < 4; ++kk) {
            const int kq = kk * 32 + quad * 8;
            s16x8 h0 = *(const s16x8*)(hr + (0 * 16 + ln) * 136 + kq);
            s16x8 h1 = *(const s16x8*)(hr + (1 * 16 + ln) * 136 + kq);
            s16x8 h2 = *(const s16x8*)(hr + (2 * 16 + ln) * 136 + kq);
            s16x8 h3 = *(const s16x8*)(hr + (3 * 16 + ln) * 136 + kq);
            acc2[0][0] = MFMA16(a2p[4 * kk + 0], h0, acc2[0][0]);
            acc2[0][1] = MFMA16(a2p[4 * kk + 0], h1, acc2[0][1]);
            acc2[0][2] = MFMA16(a2p[4 * kk + 0], h2, acc2[0][2]);
            acc2[0][3] = MFMA16(a2p[4 * kk + 0], h3, acc2[0][3]);
            acc2[1][0] = MFMA16(a2p[4 * kk + 1], h0, acc2[1][0]);
            acc2[1][1] = MFMA16(a2p[4 * kk + 1], h1, acc2[1][1]);
            acc2[1][2] = MFMA16(a2p[4 * kk + 1], h2, acc2[1][2]);
            acc2[1][3] = MFMA16(a2p[4 * kk + 1], h3, acc2[1][3]);
            acc2[2][0] = MFMA16(a2p[4 * kk + 2], h0, acc2[2][0]);
            acc2[2][1] = MFMA16(a2p[4 * kk + 2], h1, acc2[2][1]);
            acc2[2][2] = MFMA16(a2p[4 * kk + 2], h2, acc2[2][2]);
            acc2[2][3] = MFMA16(a2p[4 * kk + 2], h3, acc2[2][3]);
            acc2[3][0] = MFMA16(a2p[4 * kk + 3], h0, acc2[3][0]);
            acc2[3][1] = MFMA16(a2p[4 * kk + 3], h1, acc2[3][1]);
            acc2[3][2] = MFMA16(a2p[4 * kk + 3], h2, acc2[3][2]);
            acc2[3][3] = MFMA16(a2p[4 * kk + 3], h3, acc2[3][3]);
        }
        // ---- A1(ch+1) second half ----
#pragma unroll
        for (int kk = 4; kk < 8; ++kk) {
            a1p[2 * kk + 0] = *(const s16x8*)(A1n + kk * 32);
            a1p[2 * kk + 1] = *(const s16x8*)(A1n + 16 * NC + kk * 32);
        }
        // ---- a2p(ch+1) prefetch ----
        {
            const short* A2n = A2b + dc0 + 128;
#pragma unroll
            for (int kk = 0; kk < 4; ++kk) {
#pragma unroll
                for (int m = 0; m < 4; ++m) {
                    a2p[4 * kk + m] = *(const s16x8*)(A2n + m * 16 * NH + kk * 32);
                }
            }
        }
        // ---- GEMM1(ch+1) ----
#pragma unroll
        for (int i = 0; i < 2; ++i)
#pragma unroll
            for (int j = 0; j < 4; ++j) acc1[i][j] = (f32x4){0.f, 0.f, 0.f, 0.f};
#pragma unroll
        for (int kk = 0; kk < 8; ++kk) {
            const int kq = kk * 32 + quad * 8;
            s16x8 b0v = *(const s16x8*)(yn + (0 * 16 + ln) * 264 + kq);
            s16x8 b1v = *(const s16x8*)(yn + (1 * 16 + ln) * 264 + kq);
            s16x8 b2v = *(const s16x8*)(yn + (2 * 16 + ln) * 264 + kq);
            s16x8 b3v = *(const s16x8*)(yn + (3 * 16 + ln) * 264 + kq);
            acc1[0][0] = MFMA16(a1p[2 * kk], b0v, acc1[0][0]);
            acc1[0][1] = MFMA16(a1p[2 * kk], b1v, acc1[0][1]);
            acc1[0][2] = MFMA16(a1p[2 * kk], b2v, acc1[0][2]);
            acc1[0][3] = MFMA16(a1p[2 * kk], b3v, acc1[0][3]);
            acc1[1][0] = MFMA16(a1p[2 * kk + 1], b0v, acc1[1][0]);
            acc1[1][1] = MFMA16(a1p[2 * kk + 1], b1v, acc1[1][1]);
            acc1[1][2] = MFMA16(a1p[2 * kk + 1], b2v, acc1[1][2]);
            acc1[1][3] = MFMA16(a1p[2 * kk + 1], b3v, acc1[1][3]);
        }
    }

    // ---- tail: chunk 7 GEMM2 (a2p(7) prefetched in iter 6) ----
    {
        short* hw = &hs[1][0];
#pragma unroll
        for (int mf = 0; mf < 2; ++mf) {
            const int dbase = 32 * wid + mf * 16 + quad * 4;
            const f32x4 b1v = *(const f32x4*)(pb1 + 7 * 128 + dbase);
#pragma unroll
            for (int nf = 0; nf < 4; ++nf) {
                const int l = nf * 16 + ln;
                s16x4 hv;
#pragma unroll
                for (int r = 0; r < 4; ++r) {
                    hv[r] = f2bf(fmaxf(acc1[mf][nf][r] + b1v[r], 0.f));
                }
                *(s16x4*)(hw + l * 136 + dbase) = hv;
            }
        }
        __syncthreads();
        const short* hr = &hs[1][0];
#pragma unroll
        for (int kk = 0; kk < 4; ++kk) {
            const int kq = kk * 32 + quad * 8;
            s16x8 h0 = *(const s16x8*)(hr + (0 * 16 + ln) * 136 + kq);
            s16x8 h1 = *(const s16x8*)(hr + (1 * 16 + ln) * 136 + kq);
            s16x8 h2 = *(const s16x8*)(hr + (2 * 16 + ln) * 136 + kq);
            s16x8 h3 = *(const s16x8*)(hr + (3 * 16 + ln) * 136 + kq);
            acc2[0][0] = MFMA16(a2p[4 * kk + 0], h0, acc2[0][0]);
            acc2[0][1] = MFMA16(a2p[4 * kk + 0], h1, acc2[0][1]);
            acc2[0][2] = MFMA16(a2p[4 * kk + 0], h2, acc2[0][2]);
            acc2[0][3] = MFMA16(a2p[4 * kk + 0], h3, acc2[0][3]);
            acc2[1][0] = MFMA16(a2p[4 * kk + 1], h0, acc2[1][0]);
            acc2[1][1] = MFMA16(a2p[4 * kk + 1], h1, acc2[1][1]);
            acc2[1][2] = MFMA16(a2p[4 * kk + 1], h2, acc2[1][2]);
            acc2[1][3] = MFMA16(a2p[4 * kk + 1], h3, acc2[1][3]);
            acc2[2][0] = MFMA16(a2p[4 * kk + 2], h0, acc2[2][0]);
            acc2[2][1] = MFMA16(a2p[4 * kk + 2], h1, acc2[2][1]);
            acc2[2][2] = MFMA16(a2p[4 * kk + 2], h2, acc2[2][2]);
            acc2[2][3] = MFMA16(a2p[4 * kk + 2], h3, acc2[2][3]);
            acc2[3][0] = MFMA16(a2p[4 * kk + 3], h0, acc2[3][0]);
            acc2[3][1] = MFMA16(a2p[4 * kk + 3], h1, acc2[3][1]);
            acc2[3][2] = MFMA16(a2p[4 * kk + 3], h2, acc2[3][2]);
            acc2[3][3] = MFMA16(a2p[4 * kk + 3], h3, acc2[3][3]);
        }
    }

    // ---- epilogue: out = x + gamma * (acc2 + b2) ----
#pragma unroll
    for (int mf2 = 0; mf2 < 4; ++mf2) {
        const int cbase = 64 * wid + mf2 * 16 + quad * 4;
        const f32x4 g4 = *(const f32x4*)(gamma + cbase);
        const f32x4 b4 = *(const f32x4*)(pb2 + cbase);
#pragma unroll
        for (int r = 0; r < 4; ++r) {
            const int c = cbase + r;
            const size_t base = ((size_t)(b * NC + c)) * NL + l0 + ln;
            const float* xr = x + base;
            float* orow = out + base;
#pragma unroll
            for (int nf2 = 0; nf2 < 4; ++nf2) {
                orow[nf2 * 16] = xr[nf2 * 16] + g4[r] * (acc2[mf2][nf2][r] + b4[r]);
            }
        }
    }
}

extern "C" void kernel_launch(void* const* d_in, const int* in_sizes, int n_in,
                              void* d_out, int out_size, void* d_ws, size_t ws_size,
                              hipStream_t stream) {
    (void)in_sizes; (void)n_in; (void)out_size; (void)ws_size;
    const float* x      = (const float*)d_in[0];
    const float* tin    = (const float*)d_in[1];
    const float* dw_w   = (const float*)d_in[2];
    const float* dw_b   = (const float*)d_in[3];
    const float* film_w = (const float*)d_in[4];
    const float* film_b = (const float*)d_in[5];
    const float* pw1_w  = (const float*)d_in[6];
    const float* pw1_b  = (const float*)d_in[7];
    const float* pw2_w  = (const float*)d_in[8];
    const float* pw2_b  = (const float*)d_in[9];
    const float* gamma  = (const float*)d_in[10];
    float* out = (float*)d_out;

    char* ws = (char*)d_ws;
    short* ynt  = (short*)(ws + WS_YNT);
    short* pw1b = (short*)(ws + WS_PW1);
    short* pw2b = (short*)(ws + WS_PW2);
    float2* psum = (float2*)(ws + WS_PSUM);

    hipLaunchKernelGGL(k01_fused, dim3(NB * 256 + 256), dim3(256), 0, stream,
                       x, dw_w, dw_b, ynt, psum,
                       (const float4*)pw1_w, (const float4*)pw2_w,
                       (s16x4*)pw1b, (s16x4*)pw2b);
    hipLaunchKernelGGL(k3_gemm, dim3(NB * (NL / 64)), dim3(256), 0, stream,
                       ynt, pw1b, pw2b, pw1_b, pw2_b, tin, film_w, film_b,
                       psum, gamma, x, out);
}

// Round 10
// 276.674 us; speedup vs baseline: 1.1684x; 1.0835x over previous
//
#include <hip/hip_runtime.h>

typedef short s16x8 __attribute__((ext_vector_type(8)));
typedef short s16x4 __attribute__((ext_vector_type(4)));
typedef float f32x4 __attribute__((ext_vector_type(4)));

#define NB 16
#define NC 256
#define NL 4096
#define NH 1024
#define NE 128

// ws layout (bytes)
#define WS_YNT   0ull          // [B][L][C] bf16 transposed y   : 33554432
#define WS_PW1   33554432ull   // pw1 bf16 [1024][256]          : 524288
#define WS_PW2   34078720ull   // pw2 bf16 [256][1024]          : 524288
#define WS_AF    34603008ull   // a_film  [B][C] f32            : 16384
#define WS_BF    34619392ull   // b_film  [B][C] f32            : 16384
#define WS_PSUM  34635776ull   // [4096] float2 stat partials   : 32768

#define MFMA16(a, b, c) __builtin_amdgcn_mfma_f32_16x16x32_bf16((a), (b), (c), 0, 0, 0)

static __device__ __forceinline__ short f2bf(float f) {
    unsigned int u = __float_as_uint(f);
    u = (u + 0x7fffu + ((u >> 16) & 1u)) >> 16;
    return (short)u;
}
static __device__ __forceinline__ float bf2f(short s) {
    return __uint_as_float(((unsigned int)(unsigned short)s) << 16);
}

// ---------------- K01: dwconv+stats (blocks 0..4095) | weight cvt (4096..4351)
// k0 merged into k1's grid (R9: free — convert blocks run alongside dwconv).
__global__ __launch_bounds__(256) void k01_fused(const float* __restrict__ x,
                                                 const float* __restrict__ dw_w,
                                                 const float* __restrict__ dw_b,
                                                 short* __restrict__ ynt,
                                                 float2* __restrict__ psum,
                                                 const float4* __restrict__ pw1,
                                                 const float4* __restrict__ pw2,
                                                 s16x4* __restrict__ pw1b,
                                                 s16x4* __restrict__ pw2b) {
    __shared__ float xt[64][81];   // bank stride 81%32=17 (odd) -> <=2-way, free
    __shared__ float red1[4], red2[4];
    const int t = threadIdx.x;

    if (blockIdx.x >= NB * 256) {
        // ---- weight conversion path: 256 blocks cover 65536 float4s ----
        const int idx = (blockIdx.x - NB * 256) * 256 + t;
        const float4 a = pw1[idx];
        const float4 bq = pw2[idx];
        s16x4 oa, ob;
        oa[0] = f2bf(a.x); oa[1] = f2bf(a.y); oa[2] = f2bf(a.z); oa[3] = f2bf(a.w);
        ob[0] = f2bf(bq.x); ob[1] = f2bf(bq.y); ob[2] = f2bf(bq.z); ob[3] = f2bf(bq.w);
        pw1b[idx] = oa;
        pw2b[idx] = ob;
        return;
    }

    const int b = blockIdx.x >> 8;
    const int rem = blockIdx.x & 255;
    const int c0 = (rem >> 6) << 6;   // 4 c-blocks of 64
    const int l0 = (rem & 63) << 6;   // 64 l-blocks of 64

    // ---- stage 64 rows x 80 floats, coalesced float4 global loads ----
    const float* xb = x + ((size_t)(b * NC + c0)) * NL;
    {
#pragma unroll
        for (int j = 0; j < 5; ++j) {
            const int idx = t + 256 * j;
            const int row = idx / 20;
            const int col = idx - row * 20;
            const int lg = (l0 - 4 + col * 4) & (NL - 1);   // circular, 16B-aligned
            const float4 v = *(const float4*)(xb + (size_t)row * NL + lg);
            xt[row][col * 4 + 0] = v.x;
            xt[row][col * 4 + 1] = v.y;
            xt[row][col * 4 + 2] = v.z;
            xt[row][col * 4 + 3] = v.w;
        }
    }

    const int c = t & 63;       // lane == channel within tile
    const int w = t >> 6;       // wave id -> 16-l strip
    const float w0 = dw_w[(c0 + c) * 7 + 0], w1 = dw_w[(c0 + c) * 7 + 1],
                w2 = dw_w[(c0 + c) * 7 + 2], w3 = dw_w[(c0 + c) * 7 + 3],
                w4 = dw_w[(c0 + c) * 7 + 4], w5 = dw_w[(c0 + c) * 7 + 5],
                w6 = dw_w[(c0 + c) * 7 + 6];
    const float bb = dw_b[c0 + c];
    __syncthreads();

    float win0 = xt[c][w * 16 + 1], win1 = xt[c][w * 16 + 2], win2 = xt[c][w * 16 + 3],
          win3 = xt[c][w * 16 + 4], win4 = xt[c][w * 16 + 5], win5 = xt[c][w * 16 + 6],
          win6 = xt[c][w * 16 + 7];
    float s1 = 0.f, s2 = 0.f;
    short* yo = ynt + ((size_t)(b * NL + l0 + w * 16)) * NC + c0 + c;
#pragma unroll
    for (int i = 0; i < 16; ++i) {
        const float y = bb + w0 * win0 + w1 * win1 + w2 * win2 + w3 * win3 +
                        w4 * win4 + w5 * win5 + w6 * win6;
        s1 += y;
        s2 += y * y;
        yo[(size_t)i * NC] = f2bf(y);
        win0 = win1; win1 = win2; win2 = win3; win3 = win4; win4 = win5; win5 = win6;
        win6 = xt[c][w * 16 + i + 8];
    }
    for (int off = 32; off; off >>= 1) {
        s1 += __shfl_down(s1, off, 64);
        s2 += __shfl_down(s2, off, 64);
    }
    if ((t & 63) == 0) { red1[w] = s1; red2[w] = s2; }
    __syncthreads();
    if (t == 0) {
        psum[blockIdx.x] = make_float2(red1[0] + red1[1] + red1[2] + red1[3],
                                       red2[0] + red2[1] + red2[2] + red2[3]);
    }
}

// ---------------- K2: reduce partials + FiLM -> per-(b,c) affine --------------
// STANDALONE again (R9 lesson: folding this into k3 costs 36us -- 1024 blocks
// x 256KB film_w gather vs 16 blocks here = ~5us).
__global__ __launch_bounds__(256) void k2_finalize(const float* __restrict__ tin,
                                                   const float* __restrict__ fw,
                                                   const float* __restrict__ fb,
                                                   const float2* __restrict__ psum,
                                                   float* __restrict__ afilm,
                                                   float* __restrict__ bfilm) {
    __shared__ float r1[4], r2[4];
    const int b = blockIdx.x;
    const int c = threadIdx.x;

    const float2 v = psum[b * 256 + c];
    float s1 = v.x, s2 = v.y;
    for (int off = 32; off; off >>= 1) {
        s1 += __shfl_down(s1, off, 64);
        s2 += __shfl_down(s2, off, 64);
    }
    if ((c & 63) == 0) { r1[c >> 6] = s1; r2[c >> 6] = s2; }
    __syncthreads();
    const float sum1 = r1[0] + r1[1] + r1[2] + r1[3];
    const float sum2 = r2[0] + r2[1] + r2[2] + r2[3];

    const float n = (float)(NC * NL);
    const float mu = sum1 / n;
    const float var = sum2 / n - mu * mu;
    const float rs = rsqrtf(var + 1e-6f);

    const f32x4* tv = (const f32x4*)(tin + b * NE);
    const f32x4* wA = (const f32x4*)(fw + (size_t)c * NE);
    const f32x4* wB = (const f32x4*)(fw + (size_t)(NC + c) * NE);
    float sc = 0.f, sh = 0.f;
#pragma unroll
    for (int e = 0; e < NE / 4; ++e) {
        f32x4 tq = tv[e], aq = wA[e], bq = wB[e];
        sc += tq[0] * aq[0] + tq[1] * aq[1] + tq[2] * aq[2] + tq[3] * aq[3];
        sh += tq[0] * bq[0] + tq[1] * bq[1] + tq[2] * bq[2] + tq[3] * bq[3];
    }
    sc += fb[c];
    sh += fb[NC + c];
    const float A = rs * (1.f + sc);
    afilm[b * NC + c] = A;
    bfilm[b * NC + c] = sh - mu * A;
}

// ---------------- K3: fused yn -> GEMM1(relu) -> GEMM2 -> residual ----------
// grid: B * (L/64) blocks, 256 threads = 4 waves. Single dispatch.
// R6 body VERBATIM (best measured: 148.2us): double-buffered hs, ONE
// __syncthreads per chunk, a2p issued early in source, VGPR 108, no spill.
__global__ __launch_bounds__(256, 2) void k3_gemm(
    const short* __restrict__ ynt, const short* __restrict__ pw1b,
    const short* __restrict__ pw2b, const float* __restrict__ pb1,
    const float* __restrict__ pb2, const float* __restrict__ afilm,
    const float* __restrict__ bfilm, const float* __restrict__ gamma,
    const float* __restrict__ x, float* __restrict__ out) {
    __shared__ short yn[64 * 264];      // [l][c], stride 264 (132 words == 4 mod 32)
    __shared__ short hs[2][64 * 136];   // [l][d], stride 136 (68 words  == 4 mod 32)

    const int b = blockIdx.x >> 6;
    const int l0 = (blockIdx.x & 63) << 6;
    const int t = threadIdx.x;
    const int lane = t & 63, wid = t >> 6;
    const int ln = lane & 15, quad = lane >> 4;

    // ---- stage yn tile with the fused GroupNorm+FiLM affine ----
    {
        const int c8 = (t & 31) * 8;
        const int lrow = t >> 5;
        const f32x4 a0 = *(const f32x4*)(afilm + b * NC + c8);
        const f32x4 a1 = *(const f32x4*)(afilm + b * NC + c8 + 4);
        const f32x4 f0 = *(const f32x4*)(bfilm + b * NC + c8);
        const f32x4 f1 = *(const f32x4*)(bfilm + b * NC + c8 + 4);
        const short* ys = ynt + ((size_t)(b * NL + l0)) * NC + c8;
#pragma unroll
        for (int p = 0; p < 8; ++p) {
            const int l = p * 8 + lrow;
            s16x8 v = *(const s16x8*)(ys + (size_t)l * NC);
            s16x8 o;
#pragma unroll
            for (int j = 0; j < 4; ++j) {
                o[j]     = f2bf(a0[j] * bf2f(v[j])     + f0[j]);
                o[4 + j] = f2bf(a1[j] * bf2f(v[4 + j]) + f1[j]);
            }
            *(s16x8*)(yn + l * 264 + c8) = o;
        }
    }

    const short* A1b = pw1b + (size_t)(32 * wid + ln) * NC + quad * 8;
    const short* A2b = pw2b + (size_t)(64 * wid + ln) * NH + quad * 8;

    // A1(0) first half issued before the barrier (drained during it)
    s16x8 a1p[16];
#pragma unroll
    for (int kk = 0; kk < 4; ++kk) {
        a1p[2 * kk + 0] = *(const s16x8*)(A1b + kk * 32);
        a1p[2 * kk + 1] = *(const s16x8*)(A1b + 16 * NC + kk * 32);
    }
    __syncthreads();   // yn ready
#pragma unroll
    for (int kk = 4; kk < 8; ++kk) {
        a1p[2 * kk + 0] = *(const s16x8*)(A1b + kk * 32);
        a1p[2 * kk + 1] = *(const s16x8*)(A1b + 16 * NC + kk * 32);
    }

    // ---- a2p(0) prefetch (early in source) ----
    s16x8 a2p[16];
#pragma unroll
    for (int kk = 0; kk < 4; ++kk) {
#pragma unroll
        for (int m = 0; m < 4; ++m) {
            a2p[4 * kk + m] = *(const s16x8*)(A2b + m * 16 * NH + kk * 32);
        }
    }

    // ---- GEMM1(0) ----
    f32x4 acc1[2][4] = {};
#pragma unroll
    for (int kk = 0; kk < 8; ++kk) {
        const int kq = kk * 32 + quad * 8;
        s16x8 b0v = *(const s16x8*)(yn + (0 * 16 + ln) * 264 + kq);
        s16x8 b1v = *(const s16x8*)(yn + (1 * 16 + ln) * 264 + kq);
        s16x8 b2v = *(const s16x8*)(yn + (2 * 16 + ln) * 264 + kq);
        s16x8 b3v = *(const s16x8*)(yn + (3 * 16 + ln) * 264 + kq);
        acc1[0][0] = MFMA16(a1p[2 * kk], b0v, acc1[0][0]);
        acc1[0][1] = MFMA16(a1p[2 * kk], b1v, acc1[0][1]);
        acc1[0][2] = MFMA16(a1p[2 * kk], b2v, acc1[0][2]);
        acc1[0][3] = MFMA16(a1p[2 * kk], b3v, acc1[0][3]);
        acc1[1][0] = MFMA16(a1p[2 * kk + 1], b0v, acc1[1][0]);
        acc1[1][1] = MFMA16(a1p[2 * kk + 1], b1v, acc1[1][1]);
        acc1[1][2] = MFMA16(a1p[2 * kk + 1], b2v, acc1[1][2]);
        acc1[1][3] = MFMA16(a1p[2 * kk + 1], b3v, acc1[1][3]);
    }

    f32x4 acc2[4][4] = {};

#pragma unroll 1
    for (int ch = 0; ch < 7; ++ch) {
        const int dc0 = ch * 128;
        // ---- hs[ch&1] <- relu(acc1 + b1) ----
        short* hw = &hs[ch & 1][0];
#pragma unroll
        for (int mf = 0; mf < 2; ++mf) {
            const int dbase = 32 * wid + mf * 16 + quad * 4;
            const f32x4 b1v = *(const f32x4*)(pb1 + dc0 + dbase);
#pragma unroll
            for (int nf = 0; nf < 4; ++nf) {
                const int l = nf * 16 + ln;
                s16x4 hv;
#pragma unroll
                for (int r = 0; r < 4; ++r) {
                    hv[r] = f2bf(fmaxf(acc1[mf][nf][r] + b1v[r], 0.f));
                }
                *(s16x4*)(hw + l * 136 + dbase) = hv;
            }
        }
        __syncthreads();   // hs[ch&1] visible
        // ---- A1(ch+1) first half ----
        const short* A1n = A1b + (size_t)(dc0 + 128) * NC;
#pragma unroll
        for (int kk = 0; kk < 4; ++kk) {
            a1p[2 * kk + 0] = *(const s16x8*)(A1n + kk * 32);
            a1p[2 * kk + 1] = *(const s16x8*)(A1n + 16 * NC + kk * 32);
        }
        // ---- GEMM2(ch): acc2 += pw2[:, chunk] . h ----
        const short* hr = &hs[ch & 1][0];
#pragma unroll
        for (int kk = 0; kk < 4; ++kk) {
            const int kq = kk * 32 + quad * 8;
            s16x8 h0 = *(const s16x8*)(hr + (0 * 16 + ln) * 136 + kq);
            s16x8 h1 = *(const s16x8*)(hr + (1 * 16 + ln) * 136 + kq);
            s16x8 h2 = *(const s16x8*)(hr + (2 * 16 + ln) * 136 + kq);
            s16x8 h3 = *(const s16x8*)(hr + (3 * 16 + ln) * 136 + kq);
            acc2[0][0] = MFMA16(a2p[4 * kk + 0], h0, acc2[0][0]);
            acc2[0][1] = MFMA16(a2p[4 * kk + 0], h1, acc2[0][1]);
            acc2[0][2] = MFMA16(a2p[4 * kk + 0], h2, acc2[0][2]);
            acc2[0][3] = MFMA16(a2p[4 * kk + 0], h3, acc2[0][3]);
            acc2[1][0] = MFMA16(a2p[4 * kk + 1], h0, acc2[1][0]);
            acc2[1][1] = MFMA16(a2p[4 * kk + 1], h1, acc2[1][1]);
            acc2[1][2] = MFMA16(a2p[4 * kk + 1], h2, acc2[1][2]);
            acc2[1][3] = MFMA16(a2p[4 * kk + 1], h3, acc2[1][3]);
            acc2[2][0] = MFMA16(a2p[4 * kk + 2], h0, acc2[2][0]);
            acc2[2][1] = MFMA16(a2p[4 * kk + 2], h1, acc2[2][1]);
            acc2[2][2] = MFMA16(a2p[4 * kk + 2], h2, acc2[2][2]);
            acc2[2][3] = MFMA16(a2p[4 * kk + 2], h3, acc2[2][3]);
            acc2[3][0] = MFMA16(a2p[4 * kk + 3], h0, acc2[3][0]);
            acc2[3][1] = MFMA16(a2p[4 * kk + 3], h1, acc2[3][1]);
            acc2[3][2] = MFMA16(a2p[4 * kk + 3], h2, acc2[3][2]);
            acc2[3][3] = MFMA16(a2p[4 * kk + 3], h3, acc2[3][3]);
        }
        // ---- A1(ch+1) second half ----
#pragma unroll
        for (int kk = 4; kk < 8; ++kk) {
            a1p[2 * kk + 0] = *(const s16x8*)(A1n + kk * 32);
            a1p[2 * kk + 1] = *(const s16x8*)(A1n + 16 * NC + kk * 32);
        }
        // ---- a2p(ch+1) prefetch ----
        {
            const short* A2n = A2b + dc0 + 128;
#pragma unroll
            for (int kk = 0; kk < 4; ++kk) {
#pragma unroll
                for (int m = 0; m < 4; ++m) {
                    a2p[4 * kk + m] = *(const s16x8*)(A2n + m * 16 * NH + kk * 32);
                }
            }
        }
        // ---- GEMM1(ch+1) ----
#pragma unroll
        for (int i = 0; i < 2; ++i)
#pragma unroll
            for (int j = 0; j < 4; ++j) acc1[i][j] = (f32x4){0.f, 0.f, 0.f, 0.f};
#pragma unroll
        for (int kk = 0; kk < 8; ++kk) {
            const int kq = kk * 32 + quad * 8;
            s16x8 b0v = *(const s16x8*)(yn + (0 * 16 + ln) * 264 + kq);
            s16x8 b1v = *(const s16x8*)(yn + (1 * 16 + ln) * 264 + kq);
            s16x8 b2v = *(const s16x8*)(yn + (2 * 16 + ln) * 264 + kq);
            s16x8 b3v = *(const s16x8*)(yn + (3 * 16 + ln) * 264 + kq);
            acc1[0][0] = MFMA16(a1p[2 * kk], b0v, acc1[0][0]);
            acc1[0][1] = MFMA16(a1p[2 * kk], b1v, acc1[0][1]);
            acc1[0][2] = MFMA16(a1p[2 * kk], b2v, acc1[0][2]);
            acc1[0][3] = MFMA16(a1p[2 * kk], b3v, acc1[0][3]);
            acc1[1][0] = MFMA16(a1p[2 * kk + 1], b0v, acc1[1][0]);
            acc1[1][1] = MFMA16(a1p[2 * kk + 1], b1v, acc1[1][1]);
            acc1[1][2] = MFMA16(a1p[2 * kk + 1], b2v, acc1[1][2]);
            acc1[1][3] = MFMA16(a1p[2 * kk + 1], b3v, acc1[1][3]);
        }
    }

    // ---- tail: chunk 7 GEMM2 (a2p(7) prefetched in iter 6) ----
    {
        short* hw = &hs[1][0];
#pragma unroll
        for (int mf = 0; mf < 2; ++mf) {
            const int dbase = 32 * wid + mf * 16 + quad * 4;
            const f32x4 b1v = *(const f32x4*)(pb1 + 7 * 128 + dbase);
#pragma unroll
            for (int nf = 0; nf < 4; ++nf) {
                const int l = nf * 16 + ln;
                s16x4 hv;
#pragma unroll
                for (int r = 0; r < 4; ++r) {
                    hv[r] = f2bf(fmaxf(acc1[mf][nf][r] + b1v[r], 0.f));
                }
                *(s16x4*)(hw + l * 136 + dbase) = hv;
            }
        }
        __syncthreads();
        const short* hr = &hs[1][0];
#pragma unroll
        for (int kk = 0; kk < 4; ++kk) {
            const int kq = kk * 32 + quad * 8;
            s16x8 h0 = *(const s16x8*)(hr + (0 * 16 + ln) * 136 + kq);
            s16x8 h1 = *(const s16x8*)(hr + (1 * 16 + ln) * 136 + kq);
            s16x8 h2 = *(const s16x8*)(hr + (2 * 16 + ln) * 136 + kq);
            s16x8 h3 = *(const s16x8*)(hr + (3 * 16 + ln) * 136 + kq);
            acc2[0][0] = MFMA16(a2p[4 * kk + 0], h0, acc2[0][0]);
            acc2[0][1] = MFMA16(a2p[4 * kk + 0], h1, acc2[0][1]);
            acc2[0][2] = MFMA16(a2p[4 * kk + 0], h2, acc2[0][2]);
            acc2[0][3] = MFMA16(a2p[4 * kk + 0], h3, acc2[0][3]);
            acc2[1][0] = MFMA16(a2p[4 * kk + 1], h0, acc2[1][0]);
            acc2[1][1] = MFMA16(a2p[4 * kk + 1], h1, acc2[1][1]);
            acc2[1][2] = MFMA16(a2p[4 * kk + 1], h2, acc2[1][2]);
            acc2[1][3] = MFMA16(a2p[4 * kk + 1], h3, acc2[1][3]);
            acc2[2][0] = MFMA16(a2p[4 * kk + 2], h0, acc2[2][0]);
            acc2[2][1] = MFMA16(a2p[4 * kk + 2], h1, acc2[2][1]);
            acc2[2][2] = MFMA16(a2p[4 * kk + 2], h2, acc2[2][2]);
            acc2[2][3] = MFMA16(a2p[4 * kk + 2], h3, acc2[2][3]);
            acc2[3][0] = MFMA16(a2p[4 * kk + 3], h0, acc2[3][0]);
            acc2[3][1] = MFMA16(a2p[4 * kk + 3], h1, acc2[3][1]);
            acc2[3][2] = MFMA16(a2p[4 * kk + 3], h2, acc2[3][2]);
            acc2[3][3] = MFMA16(a2p[4 * kk + 3], h3, acc2[3][3]);
        }
    }

    // ---- epilogue: out = x + gamma * (acc2 + b2) ----
#pragma unroll
    for (int mf2 = 0; mf2 < 4; ++mf2) {
        const int cbase = 64 * wid + mf2 * 16 + quad * 4;
        const f32x4 g4 = *(const f32x4*)(gamma + cbase);
        const f32x4 b4 = *(const f32x4*)(pb2 + cbase);
#pragma unroll
        for (int r = 0; r < 4; ++r) {
            const int c = cbase + r;
            const size_t base = ((size_t)(b * NC + c)) * NL + l0 + ln;
            const float* xr = x + base;
            float* orow = out + base;
#pragma unroll
            for (int nf2 = 0; nf2 < 4; ++nf2) {
                orow[nf2 * 16] = xr[nf2 * 16] + g4[r] * (acc2[mf2][nf2][r] + b4[r]);
            }
        }
    }
}

extern "C" void kernel_launch(void* const* d_in, const int* in_sizes, int n_in,
                              void* d_out, int out_size, void* d_ws, size_t ws_size,
                              hipStream_t stream) {
    (void)in_sizes; (void)n_in; (void)out_size; (void)ws_size;
    const float* x      = (const float*)d_in[0];
    const float* tin    = (const float*)d_in[1];
    const float* dw_w   = (const float*)d_in[2];
    const float* dw_b   = (const float*)d_in[3];
    const float* film_w = (const float*)d_in[4];
    const float* film_b = (const float*)d_in[5];
    const float* pw1_w  = (const float*)d_in[6];
    const float* pw1_b  = (const float*)d_in[7];
    const float* pw2_w  = (const float*)d_in[8];
    const float* pw2_b  = (const float*)d_in[9];
    const float* gamma  = (const float*)d_in[10];
    float* out = (float*)d_out;

    char* ws = (char*)d_ws;
    short* ynt  = (short*)(ws + WS_YNT);
    short* pw1b = (short*)(ws + WS_PW1);
    short* pw2b = (short*)(ws + WS_PW2);
    float* afilm = (float*)(ws + WS_AF);
    float* bfilm = (float*)(ws + WS_BF);
    float2* psum = (float2*)(ws + WS_PSUM);

    hipLaunchKernelGGL(k01_fused, dim3(NB * 256 + 256), dim3(256), 0, stream,
                       x, dw_w, dw_b, ynt, psum,
                       (const float4*)pw1_w, (const float4*)pw2_w,
                       (s16x4*)pw1b, (s16x4*)pw2b);
    hipLaunchKernelGGL(k2_finalize, dim3(NB), dim3(256), 0, stream,
                       tin, film_w, film_b, psum, afilm, bfilm);
    hipLaunchKernelGGL(k3_gemm, dim3(NB * (NL / 64)), dim3(256), 0, stream,
                       ynt, pw1b, pw2b, pw1_b, pw2_b, afilm, bfilm, gamma, x, out);
}

// Round 11
// 275.496 us; speedup vs baseline: 1.1734x; 1.0043x over previous
//
#include <hip/hip_runtime.h>

typedef short s16x8 __attribute__((ext_vector_type(8)));
typedef short s16x4 __attribute__((ext_vector_type(4)));
typedef float f32x4 __attribute__((ext_vector_type(4)));

#define NB 16
#define NC 256
#define NL 4096
#define NH 1024
#define NE 128

// ws layout (bytes)
#define WS_YNT   0ull          // [B][L][C] bf16 transposed y   : 33554432
#define WS_PW1   33554432ull   // pw1 bf16 [1024][256]          : 524288
#define WS_PW2   34078720ull   // pw2 bf16 [256][1024]          : 524288
#define WS_AF    34603008ull   // a_film  [B][C] f32            : 16384
#define WS_BF    34619392ull   // b_film  [B][C] f32            : 16384
#define WS_PSUM  34635776ull   // [2048] float2 stat partials   : 16384

#define MFMA16(a, b, c) __builtin_amdgcn_mfma_f32_16x16x32_bf16((a), (b), (c), 0, 0, 0)

static __device__ __forceinline__ short f2bf(float f) {
    unsigned int u = __float_as_uint(f);
    u = (u + 0x7fffu + ((u >> 16) & 1u)) >> 16;
    return (short)u;
}
static __device__ __forceinline__ float bf2f(short s) {
    return __uint_as_float(((unsigned int)(unsigned short)s) << 16);
}

// ---------------- K01: dwconv+stats (blocks 0..2047) | weight cvt (2048..2303)
// v2: tile doubled to (b, 64c, 128l) -> 2048 blocks (was 4096 x 64l).
// Rationale: k1 was ~45-55us vs ~15us traffic roofline with every pipe idle --
// short-block latency exposure (900cyc HBM stage amortized over only 64l of
// conv). 2x compute per stage; xt[64][137]: stride 137%32=9 (odd) -> 2-way
// bank aliasing (free), 35.1 KB -> 4 blocks/CU.
__global__ __launch_bounds__(256) void k01_fused(const float* __restrict__ x,
                                                 const float* __restrict__ dw_w,
                                                 const float* __restrict__ dw_b,
                                                 short* __restrict__ ynt,
                                                 float2* __restrict__ psum,
                                                 const float4* __restrict__ pw1,
                                                 const float4* __restrict__ pw2,
                                                 s16x4* __restrict__ pw1b,
                                                 s16x4* __restrict__ pw2b) {
    __shared__ float xt[64][137];
    __shared__ float red1[4], red2[4];
    const int t = threadIdx.x;

    if (blockIdx.x >= NB * 128) {
        // ---- weight conversion path: 256 blocks cover 65536 float4s ----
        const int idx = (blockIdx.x - NB * 128) * 256 + t;
        const float4 a = pw1[idx];
        const float4 bq = pw2[idx];
        s16x4 oa, ob;
        oa[0] = f2bf(a.x); oa[1] = f2bf(a.y); oa[2] = f2bf(a.z); oa[3] = f2bf(a.w);
        ob[0] = f2bf(bq.x); ob[1] = f2bf(bq.y); ob[2] = f2bf(bq.z); ob[3] = f2bf(bq.w);
        pw1b[idx] = oa;
        pw2b[idx] = ob;
        return;
    }

    const int b = blockIdx.x >> 7;
    const int rem = blockIdx.x & 127;
    const int c0 = (rem >> 5) << 6;    // 4 c-blocks of 64
    const int l0 = (rem & 31) << 7;    // 32 l-blocks of 128

    // ---- stage 64 rows x 136 floats (128 + 8 halo), coalesced float4 ----
    // 64*34 = 2176 float4s; 8 full passes + 1 half pass.
    const float* xb = x + ((size_t)(b * NC + c0)) * NL;
    {
#pragma unroll
        for (int j = 0; j < 9; ++j) {
            const int idx = t + 256 * j;
            if (j == 8 && idx >= 2176) break;
            const int row = idx / 34;
            const int col = idx - row * 34;
            const int lg = (l0 - 4 + col * 4) & (NL - 1);   // circular, 16B-aligned
            const float4 v = *(const float4*)(xb + (size_t)row * NL + lg);
            xt[row][col * 4 + 0] = v.x;
            xt[row][col * 4 + 1] = v.y;
            xt[row][col * 4 + 2] = v.z;
            xt[row][col * 4 + 3] = v.w;
        }
    }

    const int c = t & 63;       // lane == channel within tile
    const int w = t >> 6;       // wave id -> 32-l strip
    const float w0 = dw_w[(c0 + c) * 7 + 0], w1 = dw_w[(c0 + c) * 7 + 1],
                w2 = dw_w[(c0 + c) * 7 + 2], w3 = dw_w[(c0 + c) * 7 + 3],
                w4 = dw_w[(c0 + c) * 7 + 4], w5 = dw_w[(c0 + c) * 7 + 5],
                w6 = dw_w[(c0 + c) * 7 + 6];
    const float bb = dw_b[c0 + c];
    __syncthreads();

    float win0 = xt[c][w * 32 + 1], win1 = xt[c][w * 32 + 2], win2 = xt[c][w * 32 + 3],
          win3 = xt[c][w * 32 + 4], win4 = xt[c][w * 32 + 5], win5 = xt[c][w * 32 + 6],
          win6 = xt[c][w * 32 + 7];
    float s1 = 0.f, s2 = 0.f;
    short* yo = ynt + ((size_t)(b * NL + l0 + w * 32)) * NC + c0 + c;
#pragma unroll
    for (int i = 0; i < 32; ++i) {
        const float y = bb + w0 * win0 + w1 * win1 + w2 * win2 + w3 * win3 +
                        w4 * win4 + w5 * win5 + w6 * win6;
        s1 += y;
        s2 += y * y;
        yo[(size_t)i * NC] = f2bf(y);
        win0 = win1; win1 = win2; win2 = win3; win3 = win4; win4 = win5; win5 = win6;
        win6 = xt[c][w * 32 + i + 8];
    }
    for (int off = 32; off; off >>= 1) {
        s1 += __shfl_down(s1, off, 64);
        s2 += __shfl_down(s2, off, 64);
    }
    if ((t & 63) == 0) { red1[w] = s1; red2[w] = s2; }
    __syncthreads();
    if (t == 0) {
        psum[blockIdx.x] = make_float2(red1[0] + red1[1] + red1[2] + red1[3],
                                       red2[0] + red2[1] + red2[2] + red2[3]);
    }
}

// ---------------- K2: reduce partials + FiLM -> per-(b,c) affine --------------
// 128 partials per batch now (2048 blocks / 16).
__global__ __launch_bounds__(256) void k2_finalize(const float* __restrict__ tin,
                                                   const float* __restrict__ fw,
                                                   const float* __restrict__ fb,
                                                   const float2* __restrict__ psum,
                                                   float* __restrict__ afilm,
                                                   float* __restrict__ bfilm) {
    __shared__ float r1[4], r2[4];
    const int b = blockIdx.x;
    const int c = threadIdx.x;

    float s1 = 0.f, s2 = 0.f;
    if (c < 128) {
        const float2 v = psum[b * 128 + c];
        s1 = v.x; s2 = v.y;
    }
    for (int off = 32; off; off >>= 1) {
        s1 += __shfl_down(s1, off, 64);
        s2 += __shfl_down(s2, off, 64);
    }
    if ((c & 63) == 0) { r1[c >> 6] = s1; r2[c >> 6] = s2; }
    __syncthreads();
    const float sum1 = r1[0] + r1[1] + r1[2] + r1[3];
    const float sum2 = r2[0] + r2[1] + r2[2] + r2[3];

    const float n = (float)(NC * NL);
    const float mu = sum1 / n;
    const float var = sum2 / n - mu * mu;
    const float rs = rsqrtf(var + 1e-6f);

    const f32x4* tv = (const f32x4*)(tin + b * NE);
    const f32x4* wA = (const f32x4*)(fw + (size_t)c * NE);
    const f32x4* wB = (const f32x4*)(fw + (size_t)(NC + c) * NE);
    float sc = 0.f, sh = 0.f;
#pragma unroll
    for (int e = 0; e < NE / 4; ++e) {
        f32x4 tq = tv[e], aq = wA[e], bq = wB[e];
        sc += tq[0] * aq[0] + tq[1] * aq[1] + tq[2] * aq[2] + tq[3] * aq[3];
        sh += tq[0] * bq[0] + tq[1] * bq[1] + tq[2] * bq[2] + tq[3] * bq[3];
    }
    sc += fb[c];
    sh += fb[NC + c];
    const float A = rs * (1.f + sc);
    afilm[b * NC + c] = A;
    bfilm[b * NC + c] = sh - mu * A;
}

// ---------------- K3: fused yn -> GEMM1(relu) -> GEMM2 -> residual ----------
// grid: B * (L/64) blocks, 256 threads = 4 waves. Single dispatch.
// R6 body VERBATIM (best measured: 148.2us): double-buffered hs, ONE
// __syncthreads per chunk, a2p issued early in source, VGPR 108, no spill.
__global__ __launch_bounds__(256, 2) void k3_gemm(
    const short* __restrict__ ynt, const short* __restrict__ pw1b,
    const short* __restrict__ pw2b, const float* __restrict__ pb1,
    const float* __restrict__ pb2, const float* __restrict__ afilm,
    const float* __restrict__ bfilm, const float* __restrict__ gamma,
    const float* __restrict__ x, float* __restrict__ out) {
    __shared__ short yn[64 * 264];      // [l][c], stride 264 (132 words == 4 mod 32)
    __shared__ short hs[2][64 * 136];   // [l][d], stride 136 (68 words  == 4 mod 32)

    const int b = blockIdx.x >> 6;
    const int l0 = (blockIdx.x & 63) << 6;
    const int t = threadIdx.x;
    const int lane = t & 63, wid = t >> 6;
    const int ln = lane & 15, quad = lane >> 4;

    // ---- stage yn tile with the fused GroupNorm+FiLM affine ----
    {
        const int c8 = (t & 31) * 8;
        const int lrow = t >> 5;
        const f32x4 a0 = *(const f32x4*)(afilm + b * NC + c8);
        const f32x4 a1 = *(const f32x4*)(afilm + b * NC + c8 + 4);
        const f32x4 f0 = *(const f32x4*)(bfilm + b * NC + c8);
        const f32x4 f1 = *(const f32x4*)(bfilm + b * NC + c8 + 4);
        const short* ys = ynt + ((size_t)(b * NL + l0)) * NC + c8;
#pragma unroll
        for (int p = 0; p < 8; ++p) {
            const int l = p * 8 + lrow;
            s16x8 v = *(const s16x8*)(ys + (size_t)l * NC);
            s16x8 o;
#pragma unroll
            for (int j = 0; j < 4; ++j) {
                o[j]     = f2bf(a0[j] * bf2f(v[j])     + f0[j]);
                o[4 + j] = f2bf(a1[j] * bf2f(v[4 + j]) + f1[j]);
            }
            *(s16x8*)(yn + l * 264 + c8) = o;
        }
    }

    const short* A1b = pw1b + (size_t)(32 * wid + ln) * NC + quad * 8;
    const short* A2b = pw2b + (size_t)(64 * wid + ln) * NH + quad * 8;

    // A1(0) first half issued before the barrier (drained during it)
    s16x8 a1p[16];
#pragma unroll
    for (int kk = 0; kk < 4; ++kk) {
        a1p[2 * kk + 0] = *(const s16x8*)(A1b + kk * 32);
        a1p[2 * kk + 1] = *(const s16x8*)(A1b + 16 * NC + kk * 32);
    }
    __syncthreads();   // yn ready
#pragma unroll
    for (int kk = 4; kk < 8; ++kk) {
        a1p[2 * kk + 0] = *(const s16x8*)(A1b + kk * 32);
        a1p[2 * kk + 1] = *(const s16x8*)(A1b + 16 * NC + kk * 32);
    }

    // ---- a2p(0) prefetch (early in source) ----
    s16x8 a2p[16];
#pragma unroll
    for (int kk = 0; kk < 4; ++kk) {
#pragma unroll
        for (int m = 0; m < 4; ++m) {
            a2p[4 * kk + m] = *(const s16x8*)(A2b + m * 16 * NH + kk * 32);
        }
    }

    // ---- GEMM1(0) ----
    f32x4 acc1[2][4] = {};
#pragma unroll
    for (int kk = 0; kk < 8; ++kk) {
        const int kq = kk * 32 + quad * 8;
        s16x8 b0v = *(const s16x8*)(yn + (0 * 16 + ln) * 264 + kq);
        s16x8 b1v = *(const s16x8*)(yn + (1 * 16 + ln) * 264 + kq);
        s16x8 b2v = *(const s16x8*)(yn + (2 * 16 + ln) * 264 + kq);
        s16x8 b3v = *(const s16x8*)(yn + (3 * 16 + ln) * 264 + kq);
        acc1[0][0] = MFMA16(a1p[2 * kk], b0v, acc1[0][0]);
        acc1[0][1] = MFMA16(a1p[2 * kk], b1v, acc1[0][1]);
        acc1[0][2] = MFMA16(a1p[2 * kk], b2v, acc1[0][2]);
        acc1[0][3] = MFMA16(a1p[2 * kk], b3v, acc1[0][3]);
        acc1[1][0] = MFMA16(a1p[2 * kk + 1], b0v, acc1[1][0]);
        acc1[1][1] = MFMA16(a1p[2 * kk + 1], b1v, acc1[1][1]);
        acc1[1][2] = MFMA16(a1p[2 * kk + 1], b2v, acc1[1][2]);
        acc1[1][3] = MFMA16(a1p[2 * kk + 1], b3v, acc1[1][3]);
    }

    f32x4 acc2[4][4] = {};

#pragma unroll 1
    for (int ch = 0; ch < 7; ++ch) {
        const int dc0 = ch * 128;
        // ---- hs[ch&1] <- relu(acc1 + b1) ----
        short* hw = &hs[ch & 1][0];
#pragma unroll
        for (int mf = 0; mf < 2; ++mf) {
            const int dbase = 32 * wid + mf * 16 + quad * 4;
            const f32x4 b1v = *(const f32x4*)(pb1 + dc0 + dbase);
#pragma unroll
            for (int nf = 0; nf < 4; ++nf) {
                const int l = nf * 16 + ln;
                s16x4 hv;
#pragma unroll
                for (int r = 0; r < 4; ++r) {
                    hv[r] = f2bf(fmaxf(acc1[mf][nf][r] + b1v[r], 0.f));
                }
                *(s16x4*)(hw + l * 136 + dbase) = hv;
            }
        }
        __syncthreads();   // hs[ch&1] visible
        // ---- A1(ch+1) first half ----
        const short* A1n = A1b + (size_t)(dc0 + 128) * NC;
#pragma unroll
        for (int kk = 0; kk < 4; ++kk) {
            a1p[2 * kk + 0] = *(const s16x8*)(A1n + kk * 32);
            a1p[2 * kk + 1] = *(const s16x8*)(A1n + 16 * NC + kk * 32);
        }
        // ---- GEMM2(ch): acc2 += pw2[:, chunk] . h ----
        const short* hr = &hs[ch & 1][0];
#pragma unroll
        for (int kk = 0; kk < 4; ++kk) {
            const int kq = kk * 32 + quad * 8;
            s16x8 h0 = *(const s16x8*)(hr + (0 * 16 + ln) * 136 + kq);
            s16x8 h1 = *(const s16x8*)(hr + (1 * 16 + ln) * 136 + kq);
            s16x8 h2 = *(const s16x8*)(hr + (2 * 16 + ln) * 136 + kq);
            s16x8 h3 = *(const s16x8*)(hr + (3 * 16 + ln) * 136 + kq);
            acc2[0][0] = MFMA16(a2p[4 * kk + 0], h0, acc2[0][0]);
            acc2[0][1] = MFMA16(a2p[4 * kk + 0], h1, acc2[0][1]);
            acc2[0][2] = MFMA16(a2p[4 * kk + 0], h2, acc2[0][2]);
            acc2[0][3] = MFMA16(a2p[4 * kk + 0], h3, acc2[0][3]);
            acc2[1][0] = MFMA16(a2p[4 * kk + 1], h0, acc2[1][0]);
            acc2[1][1] = MFMA16(a2p[4 * kk + 1], h1, acc2[1][1]);
            acc2[1][2] = MFMA16(a2p[4 * kk + 1], h2, acc2[1][2]);
            acc2[1][3] = MFMA16(a2p[4 * kk + 1], h3, acc2[1][3]);
            acc2[2][0] = MFMA16(a2p[4 * kk + 2], h0, acc2[2][0]);
            acc2[2][1] = MFMA16(a2p[4 * kk + 2], h1, acc2[2][1]);
            acc2[2][2] = MFMA16(a2p[4 * kk + 2], h2, acc2[2][2]);
            acc2[2][3] = MFMA16(a2p[4 * kk + 2], h3, acc2[2][3]);
            acc2[3][0] = MFMA16(a2p[4 * kk + 3], h0, acc2[3][0]);
            acc2[3][1] = MFMA16(a2p[4 * kk + 3], h1, acc2[3][1]);
            acc2[3][2] = MFMA16(a2p[4 * kk + 3], h2, acc2[3][2]);
            acc2[3][3] = MFMA16(a2p[4 * kk + 3], h3, acc2[3][3]);
        }
        // ---- A1(ch+1) second half ----
#pragma unroll
        for (int kk = 4; kk < 8; ++kk) {
            a1p[2 * kk + 0] = *(const s16x8*)(A1n + kk * 32);
            a1p[2 * kk + 1] = *(const s16x8*)(A1n + 16 * NC + kk * 32);
        }
        // ---- a2p(ch+1) prefetch ----
        {
            const short* A2n = A2b + dc0 + 128;
#pragma unroll
            for (int kk = 0; kk < 4; ++kk) {
#pragma unroll
                for (int m = 0; m < 4; ++m) {
                    a2p[4 * kk + m] = *(const s16x8*)(A2n + m * 16 * NH + kk * 32);
                }
            }
        }
        // ---- GEMM1(ch+1) ----
#pragma unroll
        for (int i = 0; i < 2; ++i)
#pragma unroll
            for (int j = 0; j < 4; ++j) acc1[i][j] = (f32x4){0.f, 0.f, 0.f, 0.f};
#pragma unroll
        for (int kk = 0; kk < 8; ++kk) {
            const int kq = kk * 32 + quad * 8;
            s16x8 b0v = *(const s16x8*)(yn + (0 * 16 + ln) * 264 + kq);
            s16x8 b1v = *(const s16x8*)(yn + (1 * 16 + ln) * 264 + kq);
            s16x8 b2v = *(const s16x8*)(yn + (2 * 16 + ln) * 264 + kq);
            s16x8 b3v = *(const s16x8*)(yn + (3 * 16 + ln) * 264 + kq);
            acc1[0][0] = MFMA16(a1p[2 * kk], b0v, acc1[0][0]);
            acc1[0][1] = MFMA16(a1p[2 * kk], b1v, acc1[0][1]);
            acc1[0][2] = MFMA16(a1p[2 * kk], b2v, acc1[0][2]);
            acc1[0][3] = MFMA16(a1p[2 * kk], b3v, acc1[0][3]);
            acc1[1][0] = MFMA16(a1p[2 * kk + 1], b0v, acc1[1][0]);
            acc1[1][1] = MFMA16(a1p[2 * kk + 1], b1v, acc1[1][1]);
            acc1[1][2] = MFMA16(a1p[2 * kk + 1], b2v, acc1[1][2]);
            acc1[1][3] = MFMA16(a1p[2 * kk + 1], b3v, acc1[1][3]);
        }
    }

    // ---- tail: chunk 7 GEMM2 (a2p(7) prefetched in iter 6) ----
    {
        short* hw = &hs[1][0];
#pragma unroll
        for (int mf = 0; mf < 2; ++mf) {
            const int dbase = 32 * wid + mf * 16 + quad * 4;
            const f32x4 b1v = *(const f32x4*)(pb1 + 7 * 128 + dbase);
#pragma unroll
            for (int nf = 0; nf < 4; ++nf) {
                const int l = nf * 16 + ln;
                s16x4 hv;
#pragma unroll
                for (int r = 0; r < 4; ++r) {
                    hv[r] = f2bf(fmaxf(acc1[mf][nf][r] + b1v[r], 0.f));
                }
                *(s16x4*)(hw + l * 136 + dbase) = hv;
            }
        }
        __syncthreads();
        const short* hr = &hs[1][0];
#pragma unroll
        for (int kk = 0; kk < 4; ++kk) {
            const int kq = kk * 32 + quad * 8;
            s16x8 h0 = *(const s16x8*)(hr + (0 * 16 + ln) * 136 + kq);
            s16x8 h1 = *(const s16x8*)(hr + (1 * 16 + ln) * 136 + kq);
            s16x8 h2 = *(const s16x8*)(hr + (2 * 16 + ln) * 136 + kq);
            s16x8 h3 = *(const s16x8*)(hr + (3 * 16 + ln) * 136 + kq);
            acc2[0][0] = MFMA16(a2p[4 * kk + 0], h0, acc2[0][0]);
            acc2[0][1] = MFMA16(a2p[4 * kk + 0], h1, acc2[0][1]);
            acc2[0][2] = MFMA16(a2p[4 * kk + 0], h2, acc2[0][2]);
            acc2[0][3] = MFMA16(a2p[4 * kk + 0], h3, acc2[0][3]);
            acc2[1][0] = MFMA16(a2p[4 * kk + 1], h0, acc2[1][0]);
            acc2[1][1] = MFMA16(a2p[4 * kk + 1], h1, acc2[1][1]);
            acc2[1][2] = MFMA16(a2p[4 * kk + 1], h2, acc2[1][2]);
            acc2[1][3] = MFMA16(a2p[4 * kk + 1], h3, acc2[1][3]);
            acc2[2][0] = MFMA16(a2p[4 * kk + 2], h0, acc2[2][0]);
            acc2[2][1] = MFMA16(a2p[4 * kk + 2], h1, acc2[2][1]);
            acc2[2][2] = MFMA16(a2p[4 * kk + 2], h2, acc2[2][2]);
            acc2[2][3] = MFMA16(a2p[4 * kk + 2], h3, acc2[2][3]);
            acc2[3][0] = MFMA16(a2p[4 * kk + 3], h0, acc2[3][0]);
            acc2[3][1] = MFMA16(a2p[4 * kk + 3], h1, acc2[3][1]);
            acc2[3][2] = MFMA16(a2p[4 * kk + 3], h2, acc2[3][2]);
            acc2[3][3] = MFMA16(a2p[4 * kk + 3], h3, acc2[3][3]);
        }
    }

    // ---- epilogue: out = x + gamma * (acc2 + b2) ----
#pragma unroll
    for (int mf2 = 0; mf2 < 4; ++mf2) {
        const int cbase = 64 * wid + mf2 * 16 + quad * 4;
        const f32x4 g4 = *(const f32x4*)(gamma + cbase);
        const f32x4 b4 = *(const f32x4*)(pb2 + cbase);
#pragma unroll
        for (int r = 0; r < 4; ++r) {
            const int c = cbase + r;
            const size_t base = ((size_t)(b * NC + c)) * NL + l0 + ln;
            const float* xr = x + base;
            float* orow = out + base;
#pragma unroll
            for (int nf2 = 0; nf2 < 4; ++nf2) {
                orow[nf2 * 16] = xr[nf2 * 16] + g4[r] * (acc2[mf2][nf2][r] + b4[r]);
            }
        }
    }
}

extern "C" void kernel_launch(void* const* d_in, const int* in_sizes, int n_in,
                              void* d_out, int out_size, void* d_ws, size_t ws_size,
                              hipStream_t stream) {
    (void)in_sizes; (void)n_in; (void)out_size; (void)ws_size;
    const float* x      = (const float*)d_in[0];
    const float* tin    = (const float*)d_in[1];
    const float* dw_w   = (const float*)d_in[2];
    const float* dw_b   = (const float*)d_in[3];
    const float* film_w = (const float*)d_in[4];
    const float* film_b = (const float*)d_in[5];
    const float* pw1_w  = (const float*)d_in[6];
    const float* pw1_b  = (const float*)d_in[7];
    const float* pw2_w  = (const float*)d_in[8];
    const float* pw2_b  = (const float*)d_in[9];
    const float* gamma  = (const float*)d_in[10];
    float* out = (float*)d_out;

    char* ws = (char*)d_ws;
    short* ynt  = (short*)(ws + WS_YNT);
    short* pw1b = (short*)(ws + WS_PW1);
    short* pw2b = (short*)(ws + WS_PW2);
    float* afilm = (float*)(ws + WS_AF);
    float* bfilm = (float*)(ws + WS_BF);
    float2* psum = (float2*)(ws + WS_PSUM);

    hipLaunchKernelGGL(k01_fused, dim3(NB * 128 + 256), dim3(256), 0, stream,
                       x, dw_w, dw_b, ynt, psum,
                       (const float4*)pw1_w, (const float4*)pw2_w,
                       (s16x4*)pw1b, (s16x4*)pw2b);
    hipLaunchKernelGGL(k2_finalize, dim3(NB), dim3(256), 0, stream,
                       tin, film_w, film_b, psum, afilm, bfilm);
    hipLaunchKernelGGL(k3_gemm, dim3(NB * (NL / 64)), dim3(256), 0, stream,
                       ynt, pw1b, pw2b, pw1_b, pw2_b, afilm, bfilm, gamma, x, out);
}